// Round 5
// baseline (448.370 us; speedup 1.0000x reference)
//
#include <hip/hip_runtime.h>

#define DD 160
#define HH 160
#define WW 160
#define NVOX (DD * HH * WW)
#define NPAIR (NVOX / 2)           // 2,048,000
#define NBLK2 (NPAIR / 256)        // 8000 blocks, divisible by 8
#define HALF_EXTENT 79.5f          // 0.5 * (160 - 1), identity grid analytic

// Per-voxel trilinear setup: 8 clamped element-offsets + 8 masked weights.
// Zeros padding folded into per-axis weights; loads always in-bounds.
__device__ __forceinline__ void tri_setup(float fx, float fy, float fz,
                                          int off[8], float w[8]) {
    float x0f = floorf(fx), y0f = floorf(fy), z0f = floorf(fz);
    float wx = fx - x0f, wy = fy - y0f, wz = fz - z0f;
    int x0 = (int)x0f, y0 = (int)y0f, z0 = (int)z0f;
    int x1 = x0 + 1, y1 = y0 + 1, z1 = z0 + 1;

    float ax0 = (x0 >= 0 && x0 < WW) ? (1.0f - wx) : 0.0f;
    float ax1 = (x1 >= 0 && x1 < WW) ? wx : 0.0f;
    float ay0 = (y0 >= 0 && y0 < HH) ? (1.0f - wy) : 0.0f;
    float ay1 = (y1 >= 0 && y1 < HH) ? wy : 0.0f;
    float az0 = (z0 >= 0 && z0 < DD) ? (1.0f - wz) : 0.0f;
    float az1 = (z1 >= 0 && z1 < DD) ? wz : 0.0f;

    int x0c = min(max(x0, 0), WW - 1), x1c = min(max(x1, 0), WW - 1);
    int y0c = min(max(y0, 0), HH - 1), y1c = min(max(y1, 0), HH - 1);
    int z0c = min(max(z0, 0), DD - 1), z1c = min(max(z1, 0), DD - 1);

    int zs0 = z0c * (HH * WW), zs1 = z1c * (HH * WW);
    int ys0 = y0c * WW,        ys1 = y1c * WW;

    off[0] = (zs0 + ys0 + x0c) * 3;
    off[1] = (zs0 + ys0 + x1c) * 3;
    off[2] = (zs0 + ys1 + x0c) * 3;
    off[3] = (zs0 + ys1 + x1c) * 3;
    off[4] = (zs1 + ys0 + x0c) * 3;
    off[5] = (zs1 + ys0 + x1c) * 3;
    off[6] = (zs1 + ys1 + x0c) * 3;
    off[7] = (zs1 + ys1 + x1c) * 3;

    w[0] = az0 * ay0 * ax0;
    w[1] = az0 * ay0 * ax1;
    w[2] = az0 * ay1 * ax0;
    w[3] = az0 * ay1 * ax1;
    w[4] = az1 * ay0 * ax0;
    w[5] = az1 * ay0 * ax1;
    w[6] = az1 * ay1 * ax0;
    w[7] = az1 * ay1 * ax1;
}

// One scaling-and-squaring step, 2 voxels (adjacent x) per thread.
// All 16 corner gathers are issued in one cluster, then a sched_barrier(0)
// pins them above the math so the backend cannot re-serialize them
// (round-4 post-mortem: VGPR=28 proved the scheduler batched loads, MLP~3).
template <bool SCALE_SRC, bool NT_OUT>
__global__ __launch_bounds__(256) void gs_step2(const float* __restrict__ vin,
                                                float* __restrict__ vout,
                                                float s) {
    // XCD-aware swizzle: each of 8 XCDs owns a contiguous 20-z-slice slab.
    int bid = blockIdx.x;
    int swz = (bid & 7) * (NBLK2 >> 3) + (bid >> 3);
    int pid = swz * 256 + (int)threadIdx.x;
    int vox = pid * 2;                  // even x; pair is (x, x+1), same row

    int x = vox % WW;
    int t = vox / WW;
    int y = t % HH;
    int z = t / HH;

    const float* vp = vin + (size_t)vox * 3;
    float vAx = vp[0], vAy = vp[1], vAz = vp[2];
    float vBx = vp[3], vBy = vp[4], vBz = vp[5];
    if (SCALE_SRC) { vAx *= s; vAy *= s; vAz *= s; vBx *= s; vBy *= s; vBz *= s; }

    float fxA = fmaf(vAx, HALF_EXTENT, (float)x);
    float fyA = fmaf(vAy, HALF_EXTENT, (float)y);
    float fzA = fmaf(vAz, HALF_EXTENT, (float)z);
    float fxB = fmaf(vBx, HALF_EXTENT, (float)(x + 1));
    float fyB = fmaf(vBy, HALF_EXTENT, (float)y);
    float fzB = fmaf(vBz, HALF_EXTENT, (float)z);

    int offA[8]; float wA[8];
    int offB[8]; float wB[8];
    tri_setup(fxA, fyA, fzA, offA, wA);
    tri_setup(fxB, fyB, fzB, offB, wB);

    // ---- load cluster: 16 independent dwordx3 gathers, all in flight ----
    float dA[8][3], dB[8][3];
#pragma unroll
    for (int i = 0; i < 8; ++i) {
        const float* p = vin + offA[i];
        dA[i][0] = p[0]; dA[i][1] = p[1]; dA[i][2] = p[2];
    }
#pragma unroll
    for (int i = 0; i < 8; ++i) {
        const float* p = vin + offB[i];
        dB[i][0] = p[0]; dB[i][1] = p[1]; dB[i][2] = p[2];
    }
    __builtin_amdgcn_sched_barrier(0);  // nothing crosses: loads stay clustered

    float a0 = 0.0f, a1 = 0.0f, a2 = 0.0f;
    float b0 = 0.0f, b1 = 0.0f, b2 = 0.0f;
#pragma unroll
    for (int i = 0; i < 8; ++i) {
        a0 = fmaf(wA[i], dA[i][0], a0);
        a1 = fmaf(wA[i], dA[i][1], a1);
        a2 = fmaf(wA[i], dA[i][2], a2);
    }
#pragma unroll
    for (int i = 0; i < 8; ++i) {
        b0 = fmaf(wB[i], dB[i][0], b0);
        b1 = fmaf(wB[i], dB[i][1], b1);
        b2 = fmaf(wB[i], dB[i][2], b2);
    }

    if (SCALE_SRC) { a0 *= s; a1 *= s; a2 *= s; b0 *= s; b1 *= s; b2 *= s; }

    float r0 = vAx + a0, r1 = vAy + a1, r2 = vAz + a2;
    float r3 = vBx + b0, r4 = vBy + b1, r5 = vBz + b2;

    float* op = vout + (size_t)vox * 3;
    if (NT_OUT) {
        __builtin_nontemporal_store(r0, op + 0);
        __builtin_nontemporal_store(r1, op + 1);
        __builtin_nontemporal_store(r2, op + 2);
        __builtin_nontemporal_store(r3, op + 3);
        __builtin_nontemporal_store(r4, op + 4);
        __builtin_nontemporal_store(r5, op + 5);
    } else {
        op[0] = r0; op[1] = r1; op[2] = r2;
        op[3] = r3; op[4] = r4; op[5] = r5;
    }
}

// fallback init (only used if workspace is too small for two packed buffers)
__global__ __launch_bounds__(256) void gs_init_scale(const float* __restrict__ in,
                                                     float* __restrict__ out,
                                                     int n4, float s) {
    int i = blockIdx.x * blockDim.x + threadIdx.x;
    if (i < n4) {
        float4 v = reinterpret_cast<const float4*>(in)[i];
        v.x *= s; v.y *= s; v.z *= s; v.w *= s;
        reinterpret_cast<float4*>(out)[i] = v;
    }
}

extern "C" void kernel_launch(void* const* d_in, const int* in_sizes, int n_in,
                              void* d_out, int out_size, void* d_ws, size_t ws_size,
                              hipStream_t stream) {
    const float* vel = (const float*)d_in[0];
    float* out = (float*)d_out;

    const float scale = 1.0f / 64.0f;  // 1 / 2^6
    dim3 blk(256);
    dim3 grd(NBLK2);

    const size_t buf_bytes = (size_t)NVOX * 3 * sizeof(float);  // 49.152 MB

    if (ws_size >= 2 * buf_bytes) {
        float* A = (float*)d_ws;
        float* B = (float*)((char*)d_ws + buf_bytes);

        // step 1 fused with the 1/64 scale: vel -> A
        gs_step2<true,  false><<<grd, blk, 0, stream>>>(vel, A, scale);
        // steps 2..5 ping-pong (plain stores: re-read next step)
        gs_step2<false, false><<<grd, blk, 0, stream>>>(A, B, scale);
        gs_step2<false, false><<<grd, blk, 0, stream>>>(B, A, scale);
        gs_step2<false, false><<<grd, blk, 0, stream>>>(A, B, scale);
        gs_step2<false, false><<<grd, blk, 0, stream>>>(B, A, scale);
        // step 6: A -> d_out, non-temporal (never re-read)
        gs_step2<false, true><<<grd, blk, 0, stream>>>(A, out, scale);
    } else {
        // fallback: init into out, 6 steps out<->ws, even count ends in out
        float* ws = (float*)d_ws;
        const int n4 = NVOX * 3 / 4;
        dim3 grd_init((n4 + 255) / 256);

        gs_init_scale<<<grd_init, blk, 0, stream>>>(vel, out, n4, scale);

        float* src = out;
        float* dst = ws;
        for (int i = 0; i < 6; ++i) {
            gs_step2<false, false><<<grd, blk, 0, stream>>>(src, dst, scale);
            float* tmp = src; src = dst; dst = tmp;
        }
    }
}

// Round 6
// 407.676 us; speedup vs baseline: 1.0998x; 1.0998x over previous
//
#include <hip/hip_runtime.h>

#define DD 160
#define HH 160
#define WW 160
#define NVOX (DD * HH * WW)
#define NBLOCK (NVOX / 256)        // 16000 (global-gather kernel), %8==0
#define HALF_EXTENT 79.5f          // 0.5 * (160 - 1), identity grid analytic

// ---- LDS-tiled kernel geometry ----
#define TZ 8
#define TY 8
#define TX 16
#define NTZ (DD / TZ)              // 20
#define NTY (HH / TY)              // 20
#define NTX (WW / TX)              // 10
#define NBLK_T (NTZ * NTY * NTX)   // 4000, %8==0
#define SZC (TZ + 5)               // 13 staged z cells  (pad 2 lo, 3 hi)
#define SYC (TY + 5)               // 13
#define SXC (TX + 5)               // 21
#define NSROW (SZC * SYC)          // 169 staged (z,y) rows
#define LDSF (SZC * SYC * SXC * 3) // 10647 floats = 42,588 B
#define XSTR 3                     // LDS float strides
#define YSTR (SXC * 3)             // 63
#define ZSTR (SYC * SXC * 3)       // 819

// ---------- LDS-staged step (steps 1..5) ----------
// Stage tile+halo in LDS (values at CLAMPED coords -> in-box LDS gather is
// bit-identical to the clamped global gather). Per-voxel box test on the
// UNCLAMPED floor coords; out-of-box voxels (Gaussian tail) fall back to
// the branchless global gather, so correctness never depends on the halo.
template <bool SCALE_SRC>
__global__ __launch_bounds__(256) void gs_step_lds(const float* __restrict__ vin,
                                                   float* __restrict__ vout,
                                                   float s) {
    // XCD swizzle: contiguous 500-block chunk per XCD = contiguous z-slab
    int bid = blockIdx.x;
    int swz = (bid & 7) * (NBLK_T >> 3) + (bid >> 3);
    int tx = swz % NTX;
    int tyz = swz / NTX;
    int ty = tyz % NTY;
    int tz = tyz / NTY;

    int zlo = tz * TZ - 2, ylo = ty * TY - 2, xlo = tx * TX - 2;

    __shared__ float ls[LDSF];

    int t = threadIdx.x;
    int wave = t >> 6, lane = t & 63;

    // ---- stage: 169 rows of 21 voxels; each wave does 3 rows per iter ----
    int rowSub = lane / 21;            // 0,1,2 (lane 63 idle)
    int xi = lane - rowSub * 21;
    if (rowSub < 3) {
#pragma unroll 5
        for (int j = 0; j < 15; ++j) {
            int tri = wave + j * 4;
            int r = tri * 3 + rowSub;
            if (r < NSROW) {
                int sz = r / SYC, sy = r - sz * SYC;
                int gz = min(max(zlo + sz, 0), DD - 1);
                int gy = min(max(ylo + sy, 0), HH - 1);
                int gx = min(max(xlo + xi, 0), WW - 1);
                const float* p = vin + (size_t)((gz * HH + gy) * WW + gx) * 3;
                float v0 = p[0], v1 = p[1], v2 = p[2];
                int d = (r * SXC + xi) * 3;
                ls[d + 0] = v0; ls[d + 1] = v1; ls[d + 2] = v2;
            }
        }
    }
    __syncthreads();

    // ---- compute: 4 voxels per thread ----
#pragma unroll
    for (int k = 0; k < 4; ++k) {
        int l = k * 256 + t;
        int lx = l & (TX - 1);
        int ly = (l >> 4) & (TY - 1);
        int lz = l >> 7;
        int x = tx * TX + lx, y = ty * TY + ly, z = tz * TZ + lz;

        size_t base = (size_t)((z * HH + y) * WW + x) * 3;
        float vx = vin[base + 0];
        float vy = vin[base + 1];
        float vz = vin[base + 2];
        if (SCALE_SRC) { vx *= s; vy *= s; vz *= s; }

        float fx = fmaf(vx, HALF_EXTENT, (float)x);
        float fy = fmaf(vy, HALF_EXTENT, (float)y);
        float fz = fmaf(vz, HALF_EXTENT, (float)z);

        float x0f = floorf(fx), y0f = floorf(fy), z0f = floorf(fz);
        float wx = fx - x0f, wy = fy - y0f, wz = fz - z0f;
        int x0 = (int)x0f, y0 = (int)y0f, z0 = (int)z0f;
        int x1 = x0 + 1, y1 = y0 + 1, z1 = z0 + 1;

        float ax0 = (x0 >= 0 && x0 < WW) ? (1.0f - wx) : 0.0f;
        float ax1 = (x1 >= 0 && x1 < WW) ? wx : 0.0f;
        float ay0 = (y0 >= 0 && y0 < HH) ? (1.0f - wy) : 0.0f;
        float ay1 = (y1 >= 0 && y1 < HH) ? wy : 0.0f;
        float az0 = (z0 >= 0 && z0 < DD) ? (1.0f - wz) : 0.0f;
        float az1 = (z1 >= 0 && z1 < DD) ? wz : 0.0f;

        float w000 = az0 * ay0 * ax0, w001 = az0 * ay0 * ax1;
        float w010 = az0 * ay1 * ax0, w011 = az0 * ay1 * ax1;
        float w100 = az1 * ay0 * ax0, w101 = az1 * ay0 * ax1;
        float w110 = az1 * ay1 * ax0, w111 = az1 * ay1 * ax1;

        int zr = z0 - zlo, yr = y0 - ylo, xr = x0 - xlo;
        bool inbox = ((unsigned)zr <= (unsigned)(SZC - 2)) &
                     ((unsigned)yr <= (unsigned)(SYC - 2)) &
                     ((unsigned)xr <= (unsigned)(SXC - 2));

        float acc0, acc1, acc2;
        if (inbox) {
            int f = zr * ZSTR + yr * YSTR + xr * XSTR;
            const float* q000 = ls + f;
            const float* q001 = q000 + XSTR;
            const float* q010 = q000 + YSTR;
            const float* q011 = q000 + YSTR + XSTR;
            const float* q100 = q000 + ZSTR;
            const float* q101 = q000 + ZSTR + XSTR;
            const float* q110 = q000 + ZSTR + YSTR;
            const float* q111 = q000 + ZSTR + YSTR + XSTR;

            acc0 = w000 * q000[0]; acc1 = w000 * q000[1]; acc2 = w000 * q000[2];
            acc0 = fmaf(w001, q001[0], acc0); acc1 = fmaf(w001, q001[1], acc1); acc2 = fmaf(w001, q001[2], acc2);
            acc0 = fmaf(w010, q010[0], acc0); acc1 = fmaf(w010, q010[1], acc1); acc2 = fmaf(w010, q010[2], acc2);
            acc0 = fmaf(w011, q011[0], acc0); acc1 = fmaf(w011, q011[1], acc1); acc2 = fmaf(w011, q011[2], acc2);
            acc0 = fmaf(w100, q100[0], acc0); acc1 = fmaf(w100, q100[1], acc1); acc2 = fmaf(w100, q100[2], acc2);
            acc0 = fmaf(w101, q101[0], acc0); acc1 = fmaf(w101, q101[1], acc1); acc2 = fmaf(w101, q101[2], acc2);
            acc0 = fmaf(w110, q110[0], acc0); acc1 = fmaf(w110, q110[1], acc1); acc2 = fmaf(w110, q110[2], acc2);
            acc0 = fmaf(w111, q111[0], acc0); acc1 = fmaf(w111, q111[1], acc1); acc2 = fmaf(w111, q111[2], acc2);
        } else {
            int x0c = min(max(x0, 0), WW - 1), x1c = min(max(x1, 0), WW - 1);
            int y0c = min(max(y0, 0), HH - 1), y1c = min(max(y1, 0), HH - 1);
            int z0c = min(max(z0, 0), DD - 1), z1c = min(max(z1, 0), DD - 1);
            int zs0 = z0c * (HH * WW), zs1 = z1c * (HH * WW);
            int ys0 = y0c * WW,        ys1 = y1c * WW;
            const float* p000 = vin + (size_t)(zs0 + ys0 + x0c) * 3;
            const float* p001 = vin + (size_t)(zs0 + ys0 + x1c) * 3;
            const float* p010 = vin + (size_t)(zs0 + ys1 + x0c) * 3;
            const float* p011 = vin + (size_t)(zs0 + ys1 + x1c) * 3;
            const float* p100 = vin + (size_t)(zs1 + ys0 + x0c) * 3;
            const float* p101 = vin + (size_t)(zs1 + ys0 + x1c) * 3;
            const float* p110 = vin + (size_t)(zs1 + ys1 + x0c) * 3;
            const float* p111 = vin + (size_t)(zs1 + ys1 + x1c) * 3;

            acc0 = w000 * p000[0]; acc1 = w000 * p000[1]; acc2 = w000 * p000[2];
            acc0 = fmaf(w001, p001[0], acc0); acc1 = fmaf(w001, p001[1], acc1); acc2 = fmaf(w001, p001[2], acc2);
            acc0 = fmaf(w010, p010[0], acc0); acc1 = fmaf(w010, p010[1], acc1); acc2 = fmaf(w010, p010[2], acc2);
            acc0 = fmaf(w011, p011[0], acc0); acc1 = fmaf(w011, p011[1], acc1); acc2 = fmaf(w011, p011[2], acc2);
            acc0 = fmaf(w100, p100[0], acc0); acc1 = fmaf(w100, p100[1], acc1); acc2 = fmaf(w100, p100[2], acc2);
            acc0 = fmaf(w101, p101[0], acc0); acc1 = fmaf(w101, p101[1], acc1); acc2 = fmaf(w101, p101[2], acc2);
            acc0 = fmaf(w110, p110[0], acc0); acc1 = fmaf(w110, p110[1], acc1); acc2 = fmaf(w110, p110[2], acc2);
            acc0 = fmaf(w111, p111[0], acc0); acc1 = fmaf(w111, p111[1], acc1); acc2 = fmaf(w111, p111[2], acc2);
        }

        if (SCALE_SRC) { acc0 *= s; acc1 *= s; acc2 *= s; }

        vout[base + 0] = vx + acc0;
        vout[base + 1] = vy + acc1;
        vout[base + 2] = vz + acc2;
    }
}

// ---------- global-gather step (step 6; also ws-fallback) ----------
template <bool SCALE_SRC, bool NT_OUT>
__global__ __launch_bounds__(256) void gs_step_g(const float* __restrict__ vin,
                                                 float* __restrict__ vout,
                                                 float s) {
    int bid = blockIdx.x;
    int swz = (bid & 7) * (NBLOCK >> 3) + (bid >> 3);
    int tid = swz * 256 + (int)threadIdx.x;

    int x = tid % WW;
    int t = tid / WW;
    int y = t % HH;
    int z = t / HH;

    int base = tid * 3;
    float vx = vin[base + 0];
    float vy = vin[base + 1];
    float vz = vin[base + 2];
    if (SCALE_SRC) { vx *= s; vy *= s; vz *= s; }

    float fx = fmaf(vx, HALF_EXTENT, (float)x);
    float fy = fmaf(vy, HALF_EXTENT, (float)y);
    float fz = fmaf(vz, HALF_EXTENT, (float)z);

    float x0f = floorf(fx), y0f = floorf(fy), z0f = floorf(fz);
    float wx = fx - x0f, wy = fy - y0f, wz = fz - z0f;
    int x0 = (int)x0f, y0 = (int)y0f, z0 = (int)z0f;
    int x1 = x0 + 1, y1 = y0 + 1, z1 = z0 + 1;

    float ax0 = (x0 >= 0 && x0 < WW) ? (1.0f - wx) : 0.0f;
    float ax1 = (x1 >= 0 && x1 < WW) ? wx : 0.0f;
    float ay0 = (y0 >= 0 && y0 < HH) ? (1.0f - wy) : 0.0f;
    float ay1 = (y1 >= 0 && y1 < HH) ? wy : 0.0f;
    float az0 = (z0 >= 0 && z0 < DD) ? (1.0f - wz) : 0.0f;
    float az1 = (z1 >= 0 && z1 < DD) ? wz : 0.0f;

    int x0c = min(max(x0, 0), WW - 1), x1c = min(max(x1, 0), WW - 1);
    int y0c = min(max(y0, 0), HH - 1), y1c = min(max(y1, 0), HH - 1);
    int z0c = min(max(z0, 0), DD - 1), z1c = min(max(z1, 0), DD - 1);

    int zs0 = z0c * (HH * WW), zs1 = z1c * (HH * WW);
    int ys0 = y0c * WW,        ys1 = y1c * WW;

    const float* p000 = vin + (size_t)(zs0 + ys0 + x0c) * 3;
    const float* p001 = vin + (size_t)(zs0 + ys0 + x1c) * 3;
    const float* p010 = vin + (size_t)(zs0 + ys1 + x0c) * 3;
    const float* p011 = vin + (size_t)(zs0 + ys1 + x1c) * 3;
    const float* p100 = vin + (size_t)(zs1 + ys0 + x0c) * 3;
    const float* p101 = vin + (size_t)(zs1 + ys0 + x1c) * 3;
    const float* p110 = vin + (size_t)(zs1 + ys1 + x0c) * 3;
    const float* p111 = vin + (size_t)(zs1 + ys1 + x1c) * 3;

    float a0 = p000[0], a1 = p000[1], a2 = p000[2];
    float b0 = p001[0], b1 = p001[1], b2 = p001[2];
    float c0 = p010[0], c1 = p010[1], c2 = p010[2];
    float d0 = p011[0], d1 = p011[1], d2 = p011[2];
    float e0 = p100[0], e1 = p100[1], e2 = p100[2];
    float f0 = p101[0], f1 = p101[1], f2 = p101[2];
    float g0 = p110[0], g1 = p110[1], g2 = p110[2];
    float h0 = p111[0], h1 = p111[1], h2 = p111[2];

    float w000 = az0 * ay0 * ax0, w001 = az0 * ay0 * ax1;
    float w010 = az0 * ay1 * ax0, w011 = az0 * ay1 * ax1;
    float w100 = az1 * ay0 * ax0, w101 = az1 * ay0 * ax1;
    float w110 = az1 * ay1 * ax0, w111 = az1 * ay1 * ax1;

    float acc0 = w000 * a0, acc1 = w000 * a1, acc2 = w000 * a2;
    acc0 = fmaf(w001, b0, acc0); acc1 = fmaf(w001, b1, acc1); acc2 = fmaf(w001, b2, acc2);
    acc0 = fmaf(w010, c0, acc0); acc1 = fmaf(w010, c1, acc1); acc2 = fmaf(w010, c2, acc2);
    acc0 = fmaf(w011, d0, acc0); acc1 = fmaf(w011, d1, acc1); acc2 = fmaf(w011, d2, acc2);
    acc0 = fmaf(w100, e0, acc0); acc1 = fmaf(w100, e1, acc1); acc2 = fmaf(w100, e2, acc2);
    acc0 = fmaf(w101, f0, acc0); acc1 = fmaf(w101, f1, acc1); acc2 = fmaf(w101, f2, acc2);
    acc0 = fmaf(w110, g0, acc0); acc1 = fmaf(w110, g1, acc1); acc2 = fmaf(w110, g2, acc2);
    acc0 = fmaf(w111, h0, acc0); acc1 = fmaf(w111, h1, acc1); acc2 = fmaf(w111, h2, acc2);

    if (SCALE_SRC) { acc0 *= s; acc1 *= s; acc2 *= s; }

    float r0 = vx + acc0, r1 = vy + acc1, r2 = vz + acc2;

    if (NT_OUT) {
        __builtin_nontemporal_store(r0, &vout[base + 0]);
        __builtin_nontemporal_store(r1, &vout[base + 1]);
        __builtin_nontemporal_store(r2, &vout[base + 2]);
    } else {
        vout[base + 0] = r0;
        vout[base + 1] = r1;
        vout[base + 2] = r2;
    }
}

// fallback init (only used if workspace is too small for two packed buffers)
__global__ __launch_bounds__(256) void gs_init_scale(const float* __restrict__ in,
                                                     float* __restrict__ out,
                                                     int n4, float s) {
    int i = blockIdx.x * blockDim.x + threadIdx.x;
    if (i < n4) {
        float4 v = reinterpret_cast<const float4*>(in)[i];
        v.x *= s; v.y *= s; v.z *= s; v.w *= s;
        reinterpret_cast<float4*>(out)[i] = v;
    }
}

extern "C" void kernel_launch(void* const* d_in, const int* in_sizes, int n_in,
                              void* d_out, int out_size, void* d_ws, size_t ws_size,
                              hipStream_t stream) {
    const float* vel = (const float*)d_in[0];
    float* out = (float*)d_out;

    const float scale = 1.0f / 64.0f;  // 1 / 2^6
    dim3 blk(256);
    dim3 grd_t(NBLK_T);
    dim3 grd_g(NBLOCK);

    const size_t buf_bytes = (size_t)NVOX * 3 * sizeof(float);  // 49.152 MB

    if (ws_size >= 2 * buf_bytes) {
        float* A = (float*)d_ws;
        float* B = (float*)((char*)d_ws + buf_bytes);

        // steps 1..5: LDS-tiled (halo 2 covers disp; fallback handles tails)
        gs_step_lds<true ><<<grd_t, blk, 0, stream>>>(vel, A, scale);
        gs_step_lds<false><<<grd_t, blk, 0, stream>>>(A, B, scale);
        gs_step_lds<false><<<grd_t, blk, 0, stream>>>(B, A, scale);
        gs_step_lds<false><<<grd_t, blk, 0, stream>>>(A, B, scale);
        gs_step_lds<false><<<grd_t, blk, 0, stream>>>(B, A, scale);
        // step 6: displacement ~2|N| voxels -> global gather, NT store
        gs_step_g<false, true><<<grd_g, blk, 0, stream>>>(A, out, scale);
    } else {
        // fallback: init into out, 6 global steps out<->ws, ends in out
        float* ws = (float*)d_ws;
        const int n4 = NVOX * 3 / 4;
        dim3 grd_init((n4 + 255) / 256);

        gs_init_scale<<<grd_init, blk, 0, stream>>>(vel, out, n4, scale);

        float* src = out;
        float* dst = ws;
        for (int i = 0; i < 6; ++i) {
            gs_step_g<false, false><<<grd_g, blk, 0, stream>>>(src, dst, scale);
            float* tmp = src; src = dst; dst = tmp;
        }
    }
}

// Round 7
// 375.800 us; speedup vs baseline: 1.1931x; 1.0848x over previous
//
#include <hip/hip_runtime.h>

#define DD 160
#define HH 160
#define WW 160
#define NVOX (DD * HH * WW)        // 4,096,000
#define PBLK 2000                  // persistent blocks, %8==0, fully co-resident
#define PTHR (PBLK * 256)          // 512,000 threads
#define PITER (NVOX / PTHR)        // 8 voxels per thread
#define HALF_EXTENT 79.5f          // 0.5 * (160 - 1), identity grid analytic

// Persistent, software-pipelined scaling-and-squaring step.
// Grid is fully co-resident (8 blocks/CU): no block launch/drain churn.
// Per iteration: prefetch next voxel's v, then branchless 8-corner gather on
// the current one -> after warm-up the v-read latency hides under the gather
// latency + FMA chain (serial chain ~1 memory hop per iteration, not 2).
template <bool SCALE_SRC, bool NT_OUT>
__global__ __launch_bounds__(256, 8) void gs_step_p(const float* __restrict__ vin,
                                                    float* __restrict__ vout,
                                                    float s) {
    // XCD slab swizzle: XCD k (bid&7) gets contiguous swz chunk -> contiguous
    // z-slab per iteration (L2 gather locality; FETCH_SIZE ~26 MB measured).
    int bid = blockIdx.x;
    int swz = (bid & 7) * (PBLK >> 3) + (bid >> 3);
    int vox = swz * 256 + (int)threadIdx.x;

    const float* vp0 = vin + (size_t)vox * 3;
    float vcx = vp0[0], vcy = vp0[1], vcz = vp0[2];

#pragma unroll
    for (int it = 0; it < PITER; ++it) {
        int nvox = vox + PTHR;

        // ---- prefetch next iteration's v (independent of everything below)
        float vnx = 0.0f, vny = 0.0f, vnz = 0.0f;
        if (it + 1 < PITER) {
            const float* np = vin + (size_t)nvox * 3;
            vnx = np[0]; vny = np[1]; vnz = np[2];
        }

        int x = vox % WW;
        int t2 = vox / WW;
        int y = t2 % HH;
        int z = t2 / HH;

        float vx = vcx, vy = vcy, vz = vcz;
        if (SCALE_SRC) { vx *= s; vy *= s; vz *= s; }

        float fx = fmaf(vx, HALF_EXTENT, (float)x);
        float fy = fmaf(vy, HALF_EXTENT, (float)y);
        float fz = fmaf(vz, HALF_EXTENT, (float)z);

        float x0f = floorf(fx), y0f = floorf(fy), z0f = floorf(fz);
        float wx = fx - x0f, wy = fy - y0f, wz = fz - z0f;
        int x0 = (int)x0f, y0 = (int)y0f, z0 = (int)z0f;
        int x1 = x0 + 1, y1 = y0 + 1, z1 = z0 + 1;

        // zeros padding folded into per-axis weights; loads always clamped
        float ax0 = (x0 >= 0 && x0 < WW) ? (1.0f - wx) : 0.0f;
        float ax1 = (x1 >= 0 && x1 < WW) ? wx : 0.0f;
        float ay0 = (y0 >= 0 && y0 < HH) ? (1.0f - wy) : 0.0f;
        float ay1 = (y1 >= 0 && y1 < HH) ? wy : 0.0f;
        float az0 = (z0 >= 0 && z0 < DD) ? (1.0f - wz) : 0.0f;
        float az1 = (z1 >= 0 && z1 < DD) ? wz : 0.0f;

        int x0c = min(max(x0, 0), WW - 1), x1c = min(max(x1, 0), WW - 1);
        int y0c = min(max(y0, 0), HH - 1), y1c = min(max(y1, 0), HH - 1);
        int z0c = min(max(z0, 0), DD - 1), z1c = min(max(z1, 0), DD - 1);

        int zs0 = z0c * (HH * WW), zs1 = z1c * (HH * WW);
        int ys0 = y0c * WW,        ys1 = y1c * WW;

        const float* p000 = vin + (size_t)(zs0 + ys0 + x0c) * 3;
        const float* p001 = vin + (size_t)(zs0 + ys0 + x1c) * 3;
        const float* p010 = vin + (size_t)(zs0 + ys1 + x0c) * 3;
        const float* p011 = vin + (size_t)(zs0 + ys1 + x1c) * 3;
        const float* p100 = vin + (size_t)(zs1 + ys0 + x0c) * 3;
        const float* p101 = vin + (size_t)(zs1 + ys0 + x1c) * 3;
        const float* p110 = vin + (size_t)(zs1 + ys1 + x0c) * 3;
        const float* p111 = vin + (size_t)(zs1 + ys1 + x1c) * 3;

        // 8 independent corner gathers, no control flow between them
        float a0 = p000[0], a1 = p000[1], a2 = p000[2];
        float b0 = p001[0], b1 = p001[1], b2 = p001[2];
        float c0 = p010[0], c1 = p010[1], c2 = p010[2];
        float d0 = p011[0], d1 = p011[1], d2 = p011[2];
        float e0 = p100[0], e1 = p100[1], e2 = p100[2];
        float f0 = p101[0], f1 = p101[1], f2 = p101[2];
        float g0 = p110[0], g1 = p110[1], g2 = p110[2];
        float h0 = p111[0], h1 = p111[1], h2 = p111[2];

        float w000 = az0 * ay0 * ax0, w001 = az0 * ay0 * ax1;
        float w010 = az0 * ay1 * ax0, w011 = az0 * ay1 * ax1;
        float w100 = az1 * ay0 * ax0, w101 = az1 * ay0 * ax1;
        float w110 = az1 * ay1 * ax0, w111 = az1 * ay1 * ax1;

        float acc0 = w000 * a0, acc1 = w000 * a1, acc2 = w000 * a2;
        acc0 = fmaf(w001, b0, acc0); acc1 = fmaf(w001, b1, acc1); acc2 = fmaf(w001, b2, acc2);
        acc0 = fmaf(w010, c0, acc0); acc1 = fmaf(w010, c1, acc1); acc2 = fmaf(w010, c2, acc2);
        acc0 = fmaf(w011, d0, acc0); acc1 = fmaf(w011, d1, acc1); acc2 = fmaf(w011, d2, acc2);
        acc0 = fmaf(w100, e0, acc0); acc1 = fmaf(w100, e1, acc1); acc2 = fmaf(w100, e2, acc2);
        acc0 = fmaf(w101, f0, acc0); acc1 = fmaf(w101, f1, acc1); acc2 = fmaf(w101, f2, acc2);
        acc0 = fmaf(w110, g0, acc0); acc1 = fmaf(w110, g1, acc1); acc2 = fmaf(w110, g2, acc2);
        acc0 = fmaf(w111, h0, acc0); acc1 = fmaf(w111, h1, acc1); acc2 = fmaf(w111, h2, acc2);

        if (SCALE_SRC) { acc0 *= s; acc1 *= s; acc2 *= s; }

        float r0 = vx + acc0, r1 = vy + acc1, r2 = vz + acc2;

        float* op = vout + (size_t)vox * 3;
        if (NT_OUT) {
            __builtin_nontemporal_store(r0, op + 0);
            __builtin_nontemporal_store(r1, op + 1);
            __builtin_nontemporal_store(r2, op + 2);
        } else {
            op[0] = r0; op[1] = r1; op[2] = r2;
        }

        // rotate pipeline
        vcx = vnx; vcy = vny; vcz = vnz;
        vox = nvox;
    }
}

// fallback init (only used if workspace is too small for two packed buffers)
__global__ __launch_bounds__(256) void gs_init_scale(const float* __restrict__ in,
                                                     float* __restrict__ out,
                                                     int n4, float s) {
    int i = blockIdx.x * blockDim.x + threadIdx.x;
    if (i < n4) {
        float4 v = reinterpret_cast<const float4*>(in)[i];
        v.x *= s; v.y *= s; v.z *= s; v.w *= s;
        reinterpret_cast<float4*>(out)[i] = v;
    }
}

extern "C" void kernel_launch(void* const* d_in, const int* in_sizes, int n_in,
                              void* d_out, int out_size, void* d_ws, size_t ws_size,
                              hipStream_t stream) {
    const float* vel = (const float*)d_in[0];
    float* out = (float*)d_out;

    const float scale = 1.0f / 64.0f;  // 1 / 2^6
    dim3 blk(256);
    dim3 grd(PBLK);

    const size_t buf_bytes = (size_t)NVOX * 3 * sizeof(float);  // 49.152 MB

    if (ws_size >= 2 * buf_bytes) {
        float* A = (float*)d_ws;
        float* B = (float*)((char*)d_ws + buf_bytes);

        // step 1 fused with the 1/64 scale: vel -> A
        gs_step_p<true,  false><<<grd, blk, 0, stream>>>(vel, A, scale);
        // steps 2..5 ping-pong (plain stores: re-read next step)
        gs_step_p<false, false><<<grd, blk, 0, stream>>>(A, B, scale);
        gs_step_p<false, false><<<grd, blk, 0, stream>>>(B, A, scale);
        gs_step_p<false, false><<<grd, blk, 0, stream>>>(A, B, scale);
        gs_step_p<false, false><<<grd, blk, 0, stream>>>(B, A, scale);
        // step 6: A -> d_out, non-temporal (never re-read)
        gs_step_p<false, true><<<grd, blk, 0, stream>>>(A, out, scale);
    } else {
        // fallback: init into out, 6 steps out<->ws, even count ends in out
        float* ws = (float*)d_ws;
        const int n4 = NVOX * 3 / 4;
        dim3 grd_init((n4 + 255) / 256);

        gs_init_scale<<<grd_init, blk, 0, stream>>>(vel, out, n4, scale);

        float* src = out;
        float* dst = ws;
        for (int i = 0; i < 6; ++i) {
            gs_step_p<false, false><<<grd, blk, 0, stream>>>(src, dst, scale);
            float* tmp = src; src = dst; dst = tmp;
        }
    }
}